// Round 6
// baseline (7968.823 us; speedup 1.0000x reference)
//
#include <hip/hip_runtime.h>
#include <cstdint>
#include <cstddef>

// ---------------------------------------------------------------------------
// Register-resident persistent-RNN decoder: 2-layer LSTM (H=1024) + Luong dot
// attention, T=256 sequential steps. 256 blocks x 512 threads (8 waves),
// __launch_bounds__(512,2): <=256 VGPR, all blocks co-resident.
//
// Round-6 changes vs round-5:
//  * Weights PINNED in VGPRs via asm("" : "+v") — round-5's VGPR_Count=124
//    proved the compiler rematerialized weight loads into the t-loop
//    (re-streaming ~20GB from L3 over the run). Pinning forces residency.
//  * Pre-armed pipelined polling: every gather's poll loop is issued BEFORE
//    its producer publishes (role re-split below), and gathers keep 4-8 loads
//    outstanding (rotate pipeline) -> detect ~ return-flight, not full trip.
//  * L0 waves' two serial gathers merged into one dual-vector gather2
//    (h1' + scores polled in one loop, per-vector early flagging).
//  * Constant-shift softmax: e = exp(s - 30) (identical math, no wred_max).
//
// Wave roles per block (dims k = 4b + (w&3)):
//   L0 waves 0-3 (v=w): gather x chunk v | layer-0 LSTM dim k (all 4 gates,
//                       128 pinned VGPRs) | gather2 h1' chunk + scores chunk.
//   L1 waves 4-7 (u=w-4): B-recurrent precompute | gather h0' chunk u |
//                       layer-1 LSTM dim k | C (score s=k, y2_k) |
//                       D (flash const-shift softmax + MT-row dot + tanh) ->
//                       publish x. (176 pinned VGPRs: W_ih1,W_hh1,enc,Wc2,MT)
//
// Communication: 4 mailbox regions (x, h0', h1', scores), each 8 replicated
// copies x 1024 dims x 8B (tag,val) — tag and data arrive in one atomic, no
// barriers. Producer publishes per-dim right after wred (lanes 0-7 -> 8
// copies). Block polls only copy b%8 (32 pollers/line). Chunk flags release
// to LDS; consumers are chunk-progressive. Overwrite safety of
// single-buffered regions/LDS follows from the global A->B->C->D->x chain;
// LDS h0/h1 parity double-buffered. 0xAA poison = negative tag. Zero
// __syncthreads in the main loop.
// ---------------------------------------------------------------------------

#define TSTEPS 256
#define HDIM   1024
#define NBLK   256
#define NTHR   512
#define NCOPY  8

typedef unsigned long long u64;

// ws layout in u64 units: 4 regions x 8 copies x 1024 dims
#define RX_OFF   0
#define RH0_OFF  8192
#define RH1_OFF  16384
#define RS_OFF   24576
#define WMT_OFF  32768   // MT f32[1024*1024] after regions

#define PIN(x) asm volatile("" : "+v"(x))

__device__ __forceinline__ float wred_sum(float v) {
#pragma unroll
  for (int m = 32; m >= 1; m >>= 1) v += __shfl_xor(v, m, 64);
  return v;
}
__device__ __forceinline__ void pub_store(u64* p, u64 v) {
  __hip_atomic_store(p, v, __ATOMIC_RELAXED, __HIP_MEMORY_SCOPE_AGENT);
}
__device__ __forceinline__ u64 pub_load(const u64* p) {
  return __hip_atomic_load(p, __ATOMIC_RELAXED, __HIP_MEMORY_SCOPE_AGENT);
}
__device__ __forceinline__ void lds_set(int* f, int v) {
  __hip_atomic_store(f, v, __ATOMIC_RELEASE, __HIP_MEMORY_SCOPE_WORKGROUP);
}
__device__ __forceinline__ void lds_wait(int* f, int v) {
  while (__hip_atomic_load(f, __ATOMIC_ACQUIRE, __HIP_MEMORY_SCOPE_WORKGROUP) < v) {}
}
__device__ __forceinline__ float sigf(float x) { return 1.f / (1.f + __expf(-x)); }
__device__ __forceinline__ u64 pack(int tag, float v) {
  return ((u64)(unsigned)tag << 32) | (u64)(unsigned)__float_as_uint(v);
}
__device__ __forceinline__ float lo32(u64 x) { return __uint_as_float((unsigned)x); }

// publish one dim's value to all 8 copies (value lane-uniform post-wred)
__device__ __forceinline__ void publish(u64* rbase, int k, int tag, float v, int l) {
  if (l < 8) pub_store(rbase + (size_t)l * 1024 + k, pack(tag, v));
}

// Rotate-pipelined single-vector gather: this lane's 4 slots; ~8 loads in
// flight; exits when ALL lanes found (wave reconverges), deposits float4 to
// LDS, release-flags. Detect ~ return-flight once armed.
__device__ __forceinline__ void gather1(const u64* p, int tag, float* dst,
                                        int* flag) {
  float v0 = 0.f, v1 = 0.f, v2 = 0.f, v3 = 0.f;
  unsigned ms = 0xFu;
  u64 a0 = pub_load(p + 0), a1 = pub_load(p + 1);
  u64 a2 = pub_load(p + 2), a3 = pub_load(p + 3);
  for (;;) {
    u64 c0 = pub_load(p + 0), c1 = pub_load(p + 1);
    u64 c2 = pub_load(p + 2), c3 = pub_load(p + 3);
    if ((ms & 1u) && (int)(a0 >> 32) == tag) { v0 = lo32(a0); ms &= ~1u; }
    if ((ms & 2u) && (int)(a1 >> 32) == tag) { v1 = lo32(a1); ms &= ~2u; }
    if ((ms & 4u) && (int)(a2 >> 32) == tag) { v2 = lo32(a2); ms &= ~4u; }
    if ((ms & 8u) && (int)(a3 >> 32) == tag) { v3 = lo32(a3); ms &= ~8u; }
    if (!__any(ms)) break;
    a0 = c0; a1 = c1; a2 = c2; a3 = c3;
  }
  *(float4*)dst = make_float4(v0, v1, v2, v3);
  lds_set(flag, tag);  // RELEASE: lgkmcnt(0) drains the ds_write first
}

// Dual-vector rotate gather with EARLY per-vector deposit+flag (required:
// vector B's producers transitively depend on vector A's flag).
__device__ __forceinline__ void gather2(const u64* pa, int ta, float* da, int* fa,
                                        const u64* pb, int tb, float* db, int* fb) {
  float va0 = 0.f, va1 = 0.f, va2 = 0.f, va3 = 0.f;
  float vb0 = 0.f, vb1 = 0.f, vb2 = 0.f, vb3 = 0.f;
  unsigned ma = 0xFu, mb = 0xFu;
  bool dA = false, dB = false;
  u64 a0 = pub_load(pa + 0), a1 = pub_load(pa + 1);
  u64 a2 = pub_load(pa + 2), a3 = pub_load(pa + 3);
  u64 b0 = pub_load(pb + 0), b1 = pub_load(pb + 1);
  u64 b2 = pub_load(pb + 2), b3 = pub_load(pb + 3);
  for (;;) {
    u64 c0 = pub_load(pa + 0), c1 = pub_load(pa + 1);
    u64 c2 = pub_load(pa + 2), c3 = pub_load(pa + 3);
    u64 d0 = pub_load(pb + 0), d1 = pub_load(pb + 1);
    u64 d2 = pub_load(pb + 2), d3 = pub_load(pb + 3);
    if ((ma & 1u) && (int)(a0 >> 32) == ta) { va0 = lo32(a0); ma &= ~1u; }
    if ((ma & 2u) && (int)(a1 >> 32) == ta) { va1 = lo32(a1); ma &= ~2u; }
    if ((ma & 4u) && (int)(a2 >> 32) == ta) { va2 = lo32(a2); ma &= ~4u; }
    if ((ma & 8u) && (int)(a3 >> 32) == ta) { va3 = lo32(a3); ma &= ~8u; }
    if ((mb & 1u) && (int)(b0 >> 32) == tb) { vb0 = lo32(b0); mb &= ~1u; }
    if ((mb & 2u) && (int)(b1 >> 32) == tb) { vb1 = lo32(b1); mb &= ~2u; }
    if ((mb & 4u) && (int)(b2 >> 32) == tb) { vb2 = lo32(b2); mb &= ~4u; }
    if ((mb & 8u) && (int)(b3 >> 32) == tb) { vb3 = lo32(b3); mb &= ~8u; }
    if (!dA && !__any(ma)) {
      *(float4*)da = make_float4(va0, va1, va2, va3);
      lds_set(fa, ta);
      dA = true;
    }
    if (!dB && !__any(mb)) {
      *(float4*)db = make_float4(vb0, vb1, vb2, vb3);
      lds_set(fb, tb);
      dB = true;
    }
    if (dA && dB) break;
    a0 = c0; a1 = c1; a2 = c2; a3 = c3;
    b0 = d0; b1 = d1; b2 = d2; b3 = d3;
  }
}

__global__ void __launch_bounds__(NTHR, 2) decoder_persist(
    const float* __restrict__ enc,   // [1024,1024]
    const float* __restrict__ hid,   // [2,1024]
    const float* __restrict__ cell,  // [2,1024]
    const float* __restrict__ w_ih,  // [2,4096,1024]
    const float* __restrict__ w_hh,  // [2,4096,1024]
    const float* __restrict__ b_ih,  // [2,4096]
    const float* __restrict__ b_hh,  // [2,4096]
    const float* __restrict__ wcat,  // [1024,2048]
    const float* __restrict__ bcat,  // [1024]
    float* __restrict__ out,         // [256,1024]
    float* __restrict__ ws_f) {
  u64* W = (u64*)ws_f;
  float* MTp = (float*)(W + WMT_OFF);
  const int b = blockIdx.x, tid = threadIdx.x;
  const int w = tid >> 6, l = tid & 63;
  const int j0 = b << 2;
  const int k = j0 + (w & 3);        // owned dim
  const int cp = b & (NCOPY - 1);    // polled copy
  u64* RXb  = W + RX_OFF;   const u64* RXc  = RXb  + (size_t)cp * 1024;
  u64* RH0b = W + RH0_OFF;  const u64* RH0c = RH0b + (size_t)cp * 1024;
  u64* RH1b = W + RH1_OFF;  const u64* RH1c = RH1b + (size_t)cp * 1024;
  u64* RSb  = W + RS_OFF;   const u64* RSc  = RSb  + (size_t)cp * 1024;

  __shared__ __align__(16) float bx[HDIM], bh0[2][HDIM], bh1[2][HDIM], bsc[HDIM];
  __shared__ int fx[4], fh0[4], fh1[4], fsc[4];

  // ---- pre-phase: MT[j][s] = Wc1[j]*enc[s] for j = j0..j0+3 (cooperative)
  {
    for (int idx = tid; idx < HDIM; idx += NTHR) {
      bh0[0][idx] = wcat[(size_t)(j0 + 0) * 2048 + idx];
      bh0[1][idx] = wcat[(size_t)(j0 + 1) * 2048 + idx];
      bh1[0][idx] = wcat[(size_t)(j0 + 2) * 2048 + idx];
      bh1[1][idx] = wcat[(size_t)(j0 + 3) * 2048 + idx];
    }
    __syncthreads();
#pragma unroll
    for (int rep = 0; rep < 2; ++rep) {
      int s = (w << 6) + l + (rep << 9);
      const float* er = enc + (size_t)s * 1024;
      float a0 = 0.f, a1 = 0.f, a2 = 0.f, a3 = 0.f;
      for (int hh = 0; hh < 1024; hh += 4) {
        float4 ev = *(const float4*)(er + hh);
        float4 q0 = *(const float4*)(&bh0[0][hh]);
        float4 q1 = *(const float4*)(&bh0[1][hh]);
        float4 q2 = *(const float4*)(&bh1[0][hh]);
        float4 q3 = *(const float4*)(&bh1[1][hh]);
        a0 += ev.x * q0.x + ev.y * q0.y + ev.z * q0.z + ev.w * q0.w;
        a1 += ev.x * q1.x + ev.y * q1.y + ev.z * q1.z + ev.w * q1.w;
        a2 += ev.x * q2.x + ev.y * q2.y + ev.z * q2.z + ev.w * q2.w;
        a3 += ev.x * q3.x + ev.y * q3.y + ev.z * q3.z + ev.w * q3.w;
      }
      MTp[(size_t)(j0 + 0) * 1024 + s] = a0;
      MTp[(size_t)(j0 + 1) * 1024 + s] = a1;
      MTp[(size_t)(j0 + 2) * 1024 + s] = a2;
      MTp[(size_t)(j0 + 3) * 1024 + s] = a3;
    }
    __syncthreads();
  }
  // preload initial vectors (x(0)=h1(-1)=hid[1], h0(-1)=hid[0]), init flags
  for (int idx = tid; idx < HDIM; idx += NTHR) {
    bx[idx]     = hid[HDIM + idx];
    bh0[1][idx] = hid[idx];
    bh1[1][idx] = hid[HDIM + idx];
  }
  if (tid < 4) { fx[tid] = 0; fh0[tid] = 0; fh1[tid] = 0; fsc[tid] = 0; }
  __syncthreads();

  if (w < 4) {
    // ===== L0 waves: gather x | layer-0 LSTM dim k | gather2 h1'+scores ====
    const int v = w;  // chunk id
    float wiA[4][16], whA[4][16];
#pragma unroll
    for (int g = 0; g < 4; ++g)
#pragma unroll
      for (int i = 0; i < 16; ++i) {
        wiA[g][i] = w_ih[(size_t)(g * 1024 + k) * 1024 + l + 64 * i];
        whA[g][i] = w_hh[(size_t)(g * 1024 + k) * 1024 + l + 64 * i];
        PIN(wiA[g][i]); PIN(whA[g][i]);
      }
    float bAg[4];
#pragma unroll
    for (int g = 0; g < 4; ++g) {
      bAg[g] = b_ih[g * 1024 + k] + b_hh[g * 1024 + k];
      PIN(bAg[g]);
    }
    float c0 = cell[k];

    for (int t = 0; t < TSTEPS; ++t) {
      const int gen = t + 1, par = t & 1, parp = par ^ 1;
      // recurrent h-side first (prev h0, parity LDS; flags set last step)
      lds_wait(&fh0[0], t); lds_wait(&fh0[1], t);
      lds_wait(&fh0[2], t); lds_wait(&fh0[3], t);
      float a0 = 0.f, a1 = 0.f, a2 = 0.f, a3 = 0.f;
#pragma unroll
      for (int i = 0; i < 16; ++i) {
        float hv = bh0[parp][l + 64 * i];
        a0 += whA[0][i] * hv; a1 += whA[1][i] * hv;
        a2 += whA[2][i] * hv; a3 += whA[3][i] * hv;
      }
      // gather x(t) chunk v (polls pre-armed before D(t-1) finishes elsewhere)
      if (t > 0)
        gather1(RXc + 256 * v + 4 * l, t, &bx[256 * v + 4 * l], &fx[v]);
      // x-side, chunk-progressive
#pragma unroll
      for (int c = 0; c < 4; ++c) {
        lds_wait(&fx[c], t);
#pragma unroll
        for (int i2 = 0; i2 < 4; ++i2) {
          float xv = bx[256 * c + l + 64 * i2];
          a0 += wiA[0][4 * c + i2] * xv; a1 += wiA[1][4 * c + i2] * xv;
          a2 += wiA[2][4 * c + i2] * xv; a3 += wiA[3][4 * c + i2] * xv;
        }
      }
      a0 = wred_sum(a0); a1 = wred_sum(a1);
      a2 = wred_sum(a2); a3 = wred_sum(a3);
      float gi = sigf(a0 + bAg[0]), gf = sigf(a1 + bAg[1]);
      float gg = tanhf(a2 + bAg[2]), go = sigf(a3 + bAg[3]);
      c0 = gf * c0 + gi * gg;
      publish(RH0b, k, gen, go * tanhf(c0), l);
      // merged gather: h1'(t) chunk v then scores(t) chunk v (early flags)
      gather2(RH1c + 256 * v + 4 * l, gen, &bh1[par][256 * v + 4 * l], &fh1[v],
              RSc  + 256 * v + 4 * l, gen, &bsc[256 * v + 4 * l],      &fsc[v]);
    }
  } else {
    // == L1 waves: B-rec | gather h0' | layer-1 LSTM | C | D | publish x ====
    const int u = w - 4;  // chunk id
    const float* WI1 = w_ih + (size_t)4096 * 1024;
    const float* WH1 = w_hh + (size_t)4096 * 1024;
    float wiB[4][16], whB[4][16], encr[16], wc2r[16], mtr[16];
#pragma unroll
    for (int g = 0; g < 4; ++g)
#pragma unroll
      for (int i = 0; i < 16; ++i) {
        wiB[g][i] = WI1[(size_t)(g * 1024 + k) * 1024 + l + 64 * i];
        whB[g][i] = WH1[(size_t)(g * 1024 + k) * 1024 + l + 64 * i];
        PIN(wiB[g][i]); PIN(whB[g][i]);
      }
#pragma unroll
    for (int i = 0; i < 16; ++i) {
      encr[i] = enc[(size_t)k * 1024 + l + 64 * i];
      wc2r[i] = wcat[(size_t)k * 2048 + 1024 + l + 64 * i];
      mtr[i]  = MTp[(size_t)k * 1024 + l + 64 * i];
      PIN(encr[i]); PIN(wc2r[i]); PIN(mtr[i]);
    }
    float bBg[4];
#pragma unroll
    for (int g = 0; g < 4; ++g) {
      bBg[g] = b_ih[4096 + g * 1024 + k] + b_hh[4096 + g * 1024 + k];
      PIN(bBg[g]);
    }
    float c1 = cell[HDIM + k];
    const float bcv = bcat[k];

    for (int t = 0; t < TSTEPS; ++t) {
      const int gen = t + 1, par = t & 1, parp = par ^ 1;
      // B recurrent h-side (prev h1, parity LDS; flags from last step)
      lds_wait(&fh1[0], t); lds_wait(&fh1[1], t);
      lds_wait(&fh1[2], t); lds_wait(&fh1[3], t);
      float a0 = 0.f, a1 = 0.f, a2 = 0.f, a3 = 0.f;
#pragma unroll
      for (int i = 0; i < 16; ++i) {
        float hv = bh1[parp][l + 64 * i];
        a0 += whB[0][i] * hv; a1 += whB[1][i] * hv;
        a2 += whB[2][i] * hv; a3 += whB[3][i] * hv;
      }
      // gather h0'(t) chunk u — polls armed well before A(t) publishes
      gather1(RH0c + 256 * u + 4 * l, gen, &bh0[par][256 * u + 4 * l], &fh0[u]);
      // B x-side over h0'(t), chunk-progressive
#pragma unroll
      for (int c = 0; c < 4; ++c) {
        lds_wait(&fh0[c], gen);
#pragma unroll
        for (int i2 = 0; i2 < 4; ++i2) {
          float xv = bh0[par][256 * c + l + 64 * i2];
          a0 += wiB[0][4 * c + i2] * xv; a1 += wiB[1][4 * c + i2] * xv;
          a2 += wiB[2][4 * c + i2] * xv; a3 += wiB[3][4 * c + i2] * xv;
        }
      }
      a0 = wred_sum(a0); a1 = wred_sum(a1);
      a2 = wred_sum(a2); a3 = wred_sum(a3);
      float gi = sigf(a0 + bBg[0]), gf = sigf(a1 + bBg[1]);
      float gg = tanhf(a2 + bBg[2]), go = sigf(a3 + bBg[3]);
      c1 = gf * c1 + gi * gg;
      publish(RH1b, k, gen, go * tanhf(c1), l);
      // C: score s=k and y2_k, chunk-progressive over h1'(t)
      float sc = 0.f, y2 = 0.f;
#pragma unroll
      for (int c = 0; c < 4; ++c) {
        lds_wait(&fh1[c], gen);
#pragma unroll
        for (int i2 = 0; i2 < 4; ++i2) {
          float hv = bh1[par][256 * c + l + 64 * i2];
          sc += encr[4 * c + i2] * hv;
          y2 += wc2r[4 * c + i2] * hv;
        }
      }
      sc = wred_sum(sc); y2 = wred_sum(y2);
      publish(RSb, k, gen, sc, l);
      // D: constant-shift softmax (exact: common factor cancels) + MT dot
      float den = 1e-30f, num = 0.f;
#pragma unroll
      for (int c = 0; c < 4; ++c) {
        lds_wait(&fsc[c], gen);
#pragma unroll
        for (int i2 = 0; i2 < 4; ++i2) {
          float e = __expf(bsc[256 * c + l + 64 * i2] - 30.0f);
          den += e;
          num += e * mtr[4 * c + i2];
        }
      }
      den = wred_sum(den);
      num = wred_sum(num);
      float val = tanhf(num / den + y2 + bcv);
      if (l == 0) out[(size_t)t * HDIM + k] = val;
      publish(RXb, k, gen, val, l);  // x(t+1), tag gen = t+1
    }
  }
}

extern "C" void kernel_launch(void* const* d_in, const int* in_sizes, int n_in,
                              void* d_out, int out_size, void* d_ws, size_t ws_size,
                              hipStream_t stream) {
  // d_in: 0 input_sequence (UNUSED by reference), 1 encoder_out, 2 hidden_state,
  //       3 cell_state, 4 w_ih, 5 w_hh, 6 b_ih, 7 b_hh, 8 w_concat, 9 b_concat
  const float* enc  = (const float*)d_in[1];
  const float* hid  = (const float*)d_in[2];
  const float* cel  = (const float*)d_in[3];
  const float* wih  = (const float*)d_in[4];
  const float* whh  = (const float*)d_in[5];
  const float* bih  = (const float*)d_in[6];
  const float* bhh  = (const float*)d_in[7];
  const float* wcat = (const float*)d_in[8];
  const float* bcat = (const float*)d_in[9];
  float* out = (float*)d_out;
  float* ws  = (float*)d_ws;

  hipLaunchKernelGGL(decoder_persist, dim3(NBLK), dim3(NTHR), 0, stream,
                     enc, hid, cel, wih, whh, bih, bhh, wcat, bcat, out, ws);
}